// Round 1
// baseline (418.416 us; speedup 1.0000x reference)
//
#include <hip/hip_runtime.h>
#include <hip/hip_bf16.h>
#include <math.h>

#define LEN_IN   16660
#define D_MODEL  256
#define N_HEADS  8
#define HEAD_DIM 32
#define N_LEVELS 4
#define N_POINTS 4

// Level geometry (fixed by the reference file)
__device__ __constant__ int c_H[4]     = {112, 56, 28, 14};
__device__ __constant__ int c_W[4]     = {112, 56, 28, 14};
__device__ __constant__ int c_start[4] = {0, 12544, 15680, 16464};

// ---------------------------------------------------------------------------
// Simple f32 tiled GEMM: C[M,N] = A[M,K] @ B[K,N] + bias[N]
// BM=BN=64, BK=16, 256 threads, 4x4 per thread. N,K fixed multiples of 64.
// ---------------------------------------------------------------------------
__global__ __launch_bounds__(256) void gemm_f32(
    const float* __restrict__ A, const float* __restrict__ B,
    const float* __restrict__ bias, float* __restrict__ C,
    int M, int N, int K) {
  const int BM = 64, BN = 64, BK = 16;
  __shared__ float As[BK][BM + 1];
  __shared__ float Bs[BK][BN];
  int tid = threadIdx.x;
  int brow = blockIdx.x * BM;
  int bcol = blockIdx.y * BN;
  int tx = tid & 15, ty = tid >> 4;
  float acc[4][4] = {};
  for (int k0 = 0; k0 < K; k0 += BK) {
    #pragma unroll
    for (int i = 0; i < 4; i++) {
      int idx = tid + i * 256;          // 0..1023
      int r = idx >> 4, c = idx & 15;   // A[brow+r][k0+c]
      float v = 0.f;
      int row = brow + r;
      if (row < M) v = A[(size_t)row * K + k0 + c];
      As[c][r] = v;
    }
    #pragma unroll
    for (int i = 0; i < 4; i++) {
      int idx = tid + i * 256;
      int r = idx >> 6, c = idx & 63;   // B[k0+r][bcol+c]
      Bs[r][c] = B[(size_t)(k0 + r) * N + bcol + c];
    }
    __syncthreads();
    #pragma unroll
    for (int kk = 0; kk < BK; kk++) {
      float a[4], b[4];
      #pragma unroll
      for (int i = 0; i < 4; i++) a[i] = As[kk][ty * 4 + i];
      #pragma unroll
      for (int j = 0; j < 4; j++) b[j] = Bs[kk][tx * 4 + j];
      #pragma unroll
      for (int i = 0; i < 4; i++)
        #pragma unroll
        for (int j = 0; j < 4; j++) acc[i][j] += a[i] * b[j];
    }
    __syncthreads();
  }
  #pragma unroll
  for (int i = 0; i < 4; i++) {
    int r = brow + ty * 4 + i;
    if (r >= M) continue;
    #pragma unroll
    for (int j = 0; j < 4; j++) {
      int c = bcol + tx * 4 + j;
      C[(size_t)r * N + c] = acc[i][j] + bias[c];
    }
  }
}

// ---------------------------------------------------------------------------
// Sampling + attention: one wave (64 lanes) per (query, head).
// Lanes = 2 points x 32 dims. 8 iterations cover 16 (level,point) samples.
// ---------------------------------------------------------------------------
__global__ __launch_bounds__(256) void sample_attn(
    const float* __restrict__ qp,    // (LEN, 256) projected query
    const float* __restrict__ offs,  // (LEN, 256) offsets (h,l,p,2)
    const float* __restrict__ rp,    // (LEN, 4, 2) reference points
    const float* __restrict__ Kp,    // (LEN, 256) projected key
    const float* __restrict__ Vp,    // (LEN, 256) projected value
    float* __restrict__ attn_out)    // (LEN, 256)
{
  __shared__ float lbuf[4][16];
  __shared__ float vbuf[4][16][32];

  int tid  = threadIdx.x;
  int wslot = tid >> 6;                       // wave within block (0..3)
  int lane  = tid & 63;
  int half  = lane >> 5;                      // point parity
  int d     = lane & 31;                      // head dim
  int wid   = blockIdx.x * 4 + wslot;         // global wave id
  int q     = wid >> 3;                       // query index
  int h     = wid & 7;                        // head index
  if (q >= LEN_IN) return;

  int hd = h * HEAD_DIM + d;
  float qv   = qp[(size_t)q * D_MODEL + hd];
  float offv = offs[(size_t)q * D_MODEL + hd];   // offsets for this head, elem d
  float rpv  = (d < 8) ? rp[(size_t)q * 8 + d] : 0.f;

  #pragma unroll
  for (int p2 = 0; p2 < 8; p2++) {
    int pt = p2 * 2 + half;      // 0..15 = l*4 + p
    int l  = pt >> 2;
    int pp = pt & 3;
    int H = c_H[l], W = c_W[l], start = c_start[l];

    float off_x = __shfl(offv, l * 8 + pp * 2 + 0, 32);
    float off_y = __shfl(offv, l * 8 + pp * 2 + 1, 32);
    float rp_x  = __shfl(rpv, l * 2 + 0, 32);
    float rp_y  = __shfl(rpv, l * 2 + 1, 32);

    float loc_x = rp_x + off_x / (float)W;
    float loc_y = rp_y + off_y / (float)H;
    float x = loc_x * (float)W - 0.5f;
    float y = loc_y * (float)H - 0.5f;
    float x0f = floorf(x), y0f = floorf(y);
    float lx = x - x0f, ly = y - y0f;
    int x0 = (int)x0f, y0 = (int)y0f;

    float kacc = 0.f, vacc = 0.f;
    #pragma unroll
    for (int dy = 0; dy < 2; dy++) {
      #pragma unroll
      for (int dx = 0; dx < 2; dx++) {
        int yy = y0 + dy, xx = x0 + dx;
        bool valid = (xx >= 0) & (xx < W) & (yy >= 0) & (yy < H);
        float w = (dy ? ly : 1.f - ly) * (dx ? lx : 1.f - lx);
        w = valid ? w : 0.f;
        int yc = min(max(yy, 0), H - 1);
        int xc = min(max(xx, 0), W - 1);
        size_t base = (size_t)(start + yc * W + xc) * D_MODEL + hd;
        kacc += w * Kp[base];
        vacc += w * Vp[base];
      }
    }

    // q . k_sampled, reduce over 32 dims
    float dot = qv * kacc;
    #pragma unroll
    for (int m = 16; m >= 1; m >>= 1) dot += __shfl_xor(dot, m, 32);
    if (d == 0) lbuf[wslot][pt] = dot * 0.17677669529663687f;  // 1/sqrt(32)
    vbuf[wslot][pt][d] = vacc;
  }
  __syncthreads();

  // softmax over 16 points (redundant per lane), then weighted V sum
  float m = -1e30f;
  #pragma unroll
  for (int p = 0; p < 16; p++) m = fmaxf(m, lbuf[wslot][p]);
  float e[16], s = 0.f;
  #pragma unroll
  for (int p = 0; p < 16; p++) { e[p] = __expf(lbuf[wslot][p] - m); s += e[p]; }
  float inv = 1.f / s;
  if (half == 0) {
    float o = 0.f;
    #pragma unroll
    for (int p = 0; p < 16; p++) o += e[p] * vbuf[wslot][p][d];
    attn_out[(size_t)q * D_MODEL + hd] = o * inv;
  }
}

extern "C" void kernel_launch(void* const* d_in, const int* in_sizes, int n_in,
                              void* d_out, int out_size, void* d_ws, size_t ws_size,
                              hipStream_t stream) {
  const float* query = (const float*)d_in[0];
  const float* rp    = (const float*)d_in[1];
  const float* inp   = (const float*)d_in[2];
  const float* W_q   = (const float*)d_in[5];
  const float* b_q   = (const float*)d_in[6];
  const float* W_k   = (const float*)d_in[7];
  const float* b_k   = (const float*)d_in[8];
  const float* W_v   = (const float*)d_in[9];
  const float* b_v   = (const float*)d_in[10];
  const float* W_o   = (const float*)d_in[11];
  const float* b_o   = (const float*)d_in[12];
  const float* W_off = (const float*)d_in[13];
  const float* b_off = (const float*)d_in[14];
  float* out = (float*)d_out;

  const size_t nelem = (size_t)LEN_IN * D_MODEL;  // 4,264,960
  float* qp   = (float*)d_ws;
  float* kp   = qp + nelem;
  float* vp   = kp + nelem;
  float* offs = vp + nelem;
  float* attn = offs + nelem;

  dim3 blk(256);
  dim3 ggrid((LEN_IN + 63) / 64, D_MODEL / 64);

  gemm_f32<<<ggrid, blk, 0, stream>>>(query, W_q, b_q, qp,  LEN_IN, D_MODEL, D_MODEL);
  gemm_f32<<<ggrid, blk, 0, stream>>>(inp,   W_k, b_k, kp,  LEN_IN, D_MODEL, D_MODEL);
  gemm_f32<<<ggrid, blk, 0, stream>>>(inp,   W_v, b_v, vp,  LEN_IN, D_MODEL, D_MODEL);
  gemm_f32<<<ggrid, blk, 0, stream>>>(qp,  W_off, b_off, offs, LEN_IN, D_MODEL, D_MODEL);

  int n_waves = LEN_IN * N_HEADS;           // 133280
  sample_attn<<<n_waves / 4, blk, 0, stream>>>(qp, offs, rp, kp, vp, attn);

  gemm_f32<<<ggrid, blk, 0, stream>>>(attn, W_o, b_o, out, LEN_IN, D_MODEL, D_MODEL);
}

// Round 4
// 330.275 us; speedup vs baseline: 1.2669x; 1.2669x over previous
//
#include <hip/hip_runtime.h>
#include <hip/hip_bf16.h>
#include <math.h>

#define LEN_IN   16660
#define D_MODEL  256
#define N_HEADS  8
#define HEAD_DIM 32
#define N_LEVELS 4
#define N_POINTS 4

// Level geometry (fixed by the reference file)
__device__ __constant__ int c_H[4]     = {112, 56, 28, 14};
__device__ __constant__ int c_W[4]     = {112, 56, 28, 14};
__device__ __constant__ int c_start[4] = {0, 12544, 15680, 16464};

typedef __attribute__((ext_vector_type(8))) short short8v;
typedef __attribute__((ext_vector_type(4))) float f32x4;

__device__ __forceinline__ unsigned short f2bf(float f) {
  unsigned u = __float_as_uint(f);
  unsigned r = (u + 0x7fffu + ((u >> 16) & 1u)) >> 16;
  return (unsigned short)r;
}
__device__ __forceinline__ float bf2f(unsigned short h) {
  return __uint_as_float(((unsigned)h) << 16);
}

// ---------------------------------------------------------------------------
// f32 tiled GEMM (kept for q and offset projections — position-sensitive path)
// ---------------------------------------------------------------------------
__global__ __launch_bounds__(256) void gemm_f32(
    const float* __restrict__ A, const float* __restrict__ B,
    const float* __restrict__ bias, float* __restrict__ C,
    int M, int N, int K) {
  const int BM = 64, BN = 64, BK = 16;
  __shared__ float As[BK][BM + 1];
  __shared__ float Bs[BK][BN];
  int tid = threadIdx.x;
  int brow = blockIdx.x * BM;
  int bcol = blockIdx.y * BN;
  int tx = tid & 15, ty = tid >> 4;
  float acc[4][4] = {};
  for (int k0 = 0; k0 < K; k0 += BK) {
    #pragma unroll
    for (int i = 0; i < 4; i++) {
      int idx = tid + i * 256;
      int r = idx >> 4, c = idx & 15;
      float v = 0.f;
      int row = brow + r;
      if (row < M) v = A[(size_t)row * K + k0 + c];
      As[c][r] = v;
    }
    #pragma unroll
    for (int i = 0; i < 4; i++) {
      int idx = tid + i * 256;
      int r = idx >> 6, c = idx & 63;
      Bs[r][c] = B[(size_t)(k0 + r) * N + bcol + c];
    }
    __syncthreads();
    #pragma unroll
    for (int kk = 0; kk < BK; kk++) {
      float a[4], b[4];
      #pragma unroll
      for (int i = 0; i < 4; i++) a[i] = As[kk][ty * 4 + i];
      #pragma unroll
      for (int j = 0; j < 4; j++) b[j] = Bs[kk][tx * 4 + j];
      #pragma unroll
      for (int i = 0; i < 4; i++)
        #pragma unroll
        for (int j = 0; j < 4; j++) acc[i][j] += a[i] * b[j];
    }
    __syncthreads();
  }
  #pragma unroll
  for (int i = 0; i < 4; i++) {
    int r = brow + ty * 4 + i;
    if (r >= M) continue;
    #pragma unroll
    for (int j = 0; j < 4; j++) {
      int c = bcol + tx * 4 + j;
      C[(size_t)r * N + c] = acc[i][j] + bias[c];
    }
  }
}

// ---------------------------------------------------------------------------
// Prep: transpose + bf16-cast weight matrices. Bt[n][k] = W[k][n].
// W_o additionally gets a residual (lo) matrix for hi/lo split-precision MFMA.
// ---------------------------------------------------------------------------
__global__ __launch_bounds__(256) void prep_B(
    const float* __restrict__ Wk, const float* __restrict__ Wv,
    const float* __restrict__ Wo,
    unsigned short* __restrict__ Btk, unsigned short* __restrict__ Btv,
    unsigned short* __restrict__ Btoh, unsigned short* __restrict__ Btol) {
  __shared__ float tile[64][65];
  int b = blockIdx.x;
  int mat = b >> 4, t = b & 15;
  int ti = t >> 2, tj = t & 3;  // ti: k-tile, tj: n-tile
  const float* W = (mat == 0) ? Wk : ((mat == 1) ? Wv : Wo);
  int tid = threadIdx.x;
  #pragma unroll
  for (int i = 0; i < 16; i++) {
    int idx = tid + i * 256;
    int kr = idx >> 6, nc = idx & 63;
    tile[kr][nc] = W[(size_t)(ti * 64 + kr) * 256 + tj * 64 + nc];
  }
  __syncthreads();
  #pragma unroll
  for (int i = 0; i < 16; i++) {
    int idx = tid + i * 256;
    int nr = idx >> 6, kc = idx & 63;
    float v = tile[kc][nr];
    unsigned short h = f2bf(v);
    size_t o = (size_t)(tj * 64 + nr) * 256 + ti * 64 + kc;
    if (mat == 0) Btk[o] = h;
    else if (mat == 1) Btv[o] = h;
    else {
      Btoh[o] = h;
      Btol[o] = f2bf(v - bf2f(h));
    }
  }
}

// ---------------------------------------------------------------------------
// Fused K+V projection, bf16 MFMA, hi/lo split on A for near-f32 accuracy.
// Writes packed bf16 {k | v<<16} per element for the gather kernel.
// Tile 64x64, 4 waves (2x2), each wave 32x32 = 2x2 frags of 16x16x32.
// ---------------------------------------------------------------------------
__global__ __launch_bounds__(256) void gemm_kv_mfma(
    const float* __restrict__ A,            // (M,256)
    const unsigned short* __restrict__ Btk, // (256,256) [n][k]
    const unsigned short* __restrict__ Btv,
    const float* __restrict__ bk, const float* __restrict__ bv,
    unsigned* __restrict__ kvout, int M) {
  const int P = 40;  // LDS pitch in shorts (80B: 64B data + 16B pad)
  __shared__ short Ah[64 * P], Al[64 * P], Bk[64 * P], Bv[64 * P];
  int tid = threadIdx.x;
  int m0 = blockIdx.x * 64, n0 = blockIdx.y * 64;
  int w = tid >> 6, l = tid & 63;
  int r = l & 15, g = l >> 4;
  int mi = (w >> 1) * 32, ni = (w & 1) * 32;
  int sm = tid >> 2, sp = tid & 3;  // staging: row, 8-elem chunk

  f32x4 acck[2][2], accv[2][2];
  #pragma unroll
  for (int a = 0; a < 2; a++)
    #pragma unroll
    for (int b = 0; b < 2; b++) {
      acck[a][b] = (f32x4){0.f, 0.f, 0.f, 0.f};
      accv[a][b] = (f32x4){0.f, 0.f, 0.f, 0.f};
    }

  for (int k0 = 0; k0 < 256; k0 += 32) {
    // stage A tile (hi/lo bf16)
    int gm = m0 + sm;
    float f[8];
    if (gm < M) {
      const float* src = A + (size_t)gm * 256 + k0 + sp * 8;
      float4 u0 = *(const float4*)src;
      float4 u1 = *(const float4*)(src + 4);
      f[0] = u0.x; f[1] = u0.y; f[2] = u0.z; f[3] = u0.w;
      f[4] = u1.x; f[5] = u1.y; f[6] = u1.z; f[7] = u1.w;
    } else {
      #pragma unroll
      for (int j = 0; j < 8; j++) f[j] = 0.f;
    }
    short8v hv, lv;
    #pragma unroll
    for (int j = 0; j < 8; j++) {
      unsigned short h = f2bf(f[j]);
      hv[j] = (short)h;
      lv[j] = (short)f2bf(f[j] - bf2f(h));
    }
    *(short8v*)&Ah[sm * P + sp * 8] = hv;
    *(short8v*)&Al[sm * P + sp * 8] = lv;
    // stage B tiles (already bf16, transposed [n][k])
    *(short8v*)&Bk[sm * P + sp * 8] =
        *(const short8v*)&Btk[(size_t)(n0 + sm) * 256 + k0 + sp * 8];
    *(short8v*)&Bv[sm * P + sp * 8] =
        *(const short8v*)&Btv[(size_t)(n0 + sm) * 256 + k0 + sp * 8];
    __syncthreads();

    short8v ah[2], al[2], fbk[2], fbv[2];
    #pragma unroll
    for (int a = 0; a < 2; a++) {
      ah[a] = *(short8v*)&Ah[(mi + a * 16 + r) * P + g * 8];
      al[a] = *(short8v*)&Al[(mi + a * 16 + r) * P + g * 8];
    }
    #pragma unroll
    for (int b = 0; b < 2; b++) {
      fbk[b] = *(short8v*)&Bk[(ni + b * 16 + r) * P + g * 8];
      fbv[b] = *(short8v*)&Bv[(ni + b * 16 + r) * P + g * 8];
    }
    #pragma unroll
    for (int a = 0; a < 2; a++)
      #pragma unroll
      for (int b = 0; b < 2; b++) {
        acck[a][b] = __builtin_amdgcn_mfma_f32_16x16x32_bf16(ah[a], fbk[b], acck[a][b], 0, 0, 0);
        acck[a][b] = __builtin_amdgcn_mfma_f32_16x16x32_bf16(al[a], fbk[b], acck[a][b], 0, 0, 0);
        accv[a][b] = __builtin_amdgcn_mfma_f32_16x16x32_bf16(ah[a], fbv[b], accv[a][b], 0, 0, 0);
        accv[a][b] = __builtin_amdgcn_mfma_f32_16x16x32_bf16(al[a], fbv[b], accv[a][b], 0, 0, 0);
      }
    __syncthreads();
  }

  #pragma unroll
  for (int a = 0; a < 2; a++)
    #pragma unroll
    for (int b = 0; b < 2; b++) {
      int col = n0 + ni + b * 16 + r;
      float bkc = bk[col], bvc = bv[col];
      #pragma unroll
      for (int i = 0; i < 4; i++) {
        int row = m0 + mi + a * 16 + g * 4 + i;
        if (row < M) {
          unsigned pk = f2bf(acck[a][b][i] + bkc);
          unsigned pv = f2bf(accv[a][b][i] + bvc);
          kvout[(size_t)row * 256 + col] = pk | (pv << 16);
        }
      }
    }
}

// ---------------------------------------------------------------------------
// Output projection, bf16 MFMA with hi/lo split on BOTH operands (~f32 acc).
// ---------------------------------------------------------------------------
__global__ __launch_bounds__(256) void gemm_o_mfma(
    const float* __restrict__ A,             // (M,256) attn
    const unsigned short* __restrict__ Bth,  // (256,256) [n][k]
    const unsigned short* __restrict__ Btl,
    const float* __restrict__ bo, float* __restrict__ C, int M) {
  const int P = 40;
  __shared__ short Ah[64 * P], Al[64 * P], Bh[64 * P], Bl[64 * P];
  int tid = threadIdx.x;
  int m0 = blockIdx.x * 64, n0 = blockIdx.y * 64;
  int w = tid >> 6, l = tid & 63;
  int r = l & 15, g = l >> 4;
  int mi = (w >> 1) * 32, ni = (w & 1) * 32;
  int sm = tid >> 2, sp = tid & 3;

  f32x4 acc[2][2];
  #pragma unroll
  for (int a = 0; a < 2; a++)
    #pragma unroll
    for (int b = 0; b < 2; b++) acc[a][b] = (f32x4){0.f, 0.f, 0.f, 0.f};

  for (int k0 = 0; k0 < 256; k0 += 32) {
    int gm = m0 + sm;
    float f[8];
    if (gm < M) {
      const float* src = A + (size_t)gm * 256 + k0 + sp * 8;
      float4 u0 = *(const float4*)src;
      float4 u1 = *(const float4*)(src + 4);
      f[0] = u0.x; f[1] = u0.y; f[2] = u0.z; f[3] = u0.w;
      f[4] = u1.x; f[5] = u1.y; f[6] = u1.z; f[7] = u1.w;
    } else {
      #pragma unroll
      for (int j = 0; j < 8; j++) f[j] = 0.f;
    }
    short8v hv, lv;
    #pragma unroll
    for (int j = 0; j < 8; j++) {
      unsigned short h = f2bf(f[j]);
      hv[j] = (short)h;
      lv[j] = (short)f2bf(f[j] - bf2f(h));
    }
    *(short8v*)&Ah[sm * P + sp * 8] = hv;
    *(short8v*)&Al[sm * P + sp * 8] = lv;
    *(short8v*)&Bh[sm * P + sp * 8] =
        *(const short8v*)&Bth[(size_t)(n0 + sm) * 256 + k0 + sp * 8];
    *(short8v*)&Bl[sm * P + sp * 8] =
        *(const short8v*)&Btl[(size_t)(n0 + sm) * 256 + k0 + sp * 8];
    __syncthreads();

    short8v ah[2], al[2], bh[2], bl[2];
    #pragma unroll
    for (int a = 0; a < 2; a++) {
      ah[a] = *(short8v*)&Ah[(mi + a * 16 + r) * P + g * 8];
      al[a] = *(short8v*)&Al[(mi + a * 16 + r) * P + g * 8];
    }
    #pragma unroll
    for (int b = 0; b < 2; b++) {
      bh[b] = *(short8v*)&Bh[(ni + b * 16 + r) * P + g * 8];
      bl[b] = *(short8v*)&Bl[(ni + b * 16 + r) * P + g * 8];
    }
    #pragma unroll
    for (int a = 0; a < 2; a++)
      #pragma unroll
      for (int b = 0; b < 2; b++) {
        acc[a][b] = __builtin_amdgcn_mfma_f32_16x16x32_bf16(ah[a], bh[b], acc[a][b], 0, 0, 0);
        acc[a][b] = __builtin_amdgcn_mfma_f32_16x16x32_bf16(al[a], bh[b], acc[a][b], 0, 0, 0);
        acc[a][b] = __builtin_amdgcn_mfma_f32_16x16x32_bf16(ah[a], bl[b], acc[a][b], 0, 0, 0);
      }
    __syncthreads();
  }

  #pragma unroll
  for (int a = 0; a < 2; a++)
    #pragma unroll
    for (int b = 0; b < 2; b++) {
      int col = n0 + ni + b * 16 + r;
      float boc = bo[col];
      #pragma unroll
      for (int i = 0; i < 4; i++) {
        int row = m0 + mi + a * 16 + g * 4 + i;
        if (row < M) C[(size_t)row * 256 + col] = acc[a][b][i] + boc;
      }
    }
}

// ---------------------------------------------------------------------------
// Sampling + attention: one wave per (query, head); packed bf16 K/V gather.
// ---------------------------------------------------------------------------
__global__ __launch_bounds__(256) void sample_attn(
    const float* __restrict__ qp,
    const float* __restrict__ offs,
    const float* __restrict__ rp,
    const unsigned* __restrict__ kv,   // packed {k_bf16 | v_bf16<<16}
    float* __restrict__ attn_out) {
  __shared__ float lbuf[4][16];
  __shared__ float vbuf[4][16][32];

  int tid = threadIdx.x;
  int wslot = tid >> 6;
  int lane = tid & 63;
  int half = lane >> 5;
  int d = lane & 31;
  int wid = blockIdx.x * 4 + wslot;
  int q = wid >> 3;
  int h = wid & 7;
  if (q >= LEN_IN) return;

  int hd = h * HEAD_DIM + d;
  float qv = qp[(size_t)q * D_MODEL + hd];
  float offv = offs[(size_t)q * D_MODEL + hd];
  float rpv = (d < 8) ? rp[(size_t)q * 8 + d] : 0.f;

  #pragma unroll
  for (int p2 = 0; p2 < 8; p2++) {
    int pt = p2 * 2 + half;
    int l = pt >> 2;
    int pp = pt & 3;
    int H = c_H[l], W = c_W[l], start = c_start[l];

    float off_x = __shfl(offv, l * 8 + pp * 2 + 0, 32);
    float off_y = __shfl(offv, l * 8 + pp * 2 + 1, 32);
    float rp_x = __shfl(rpv, l * 2 + 0, 32);
    float rp_y = __shfl(rpv, l * 2 + 1, 32);

    float loc_x = rp_x + off_x / (float)W;
    float loc_y = rp_y + off_y / (float)H;
    float x = loc_x * (float)W - 0.5f;
    float y = loc_y * (float)H - 0.5f;
    float x0f = floorf(x), y0f = floorf(y);
    float lx = x - x0f, ly = y - y0f;
    int x0 = (int)x0f, y0 = (int)y0f;

    float kacc = 0.f, vacc = 0.f;
    #pragma unroll
    for (int dy = 0; dy < 2; dy++) {
      #pragma unroll
      for (int dx = 0; dx < 2; dx++) {
        int yy = y0 + dy, xx = x0 + dx;
        bool valid = (xx >= 0) & (xx < W) & (yy >= 0) & (yy < H);
        float wgt = (dy ? ly : 1.f - ly) * (dx ? lx : 1.f - lx);
        wgt = valid ? wgt : 0.f;
        int yc = min(max(yy, 0), H - 1);
        int xc = min(max(xx, 0), W - 1);
        unsigned wv = kv[(size_t)(start + yc * W + xc) * D_MODEL + hd];
        kacc += wgt * __uint_as_float(wv << 16);
        vacc += wgt * __uint_as_float(wv & 0xffff0000u);
      }
    }

    float dot = qv * kacc;
    #pragma unroll
    for (int m = 16; m >= 1; m >>= 1) dot += __shfl_xor(dot, m, 32);
    if (d == 0) lbuf[wslot][pt] = dot * 0.17677669529663687f;
    vbuf[wslot][pt][d] = vacc;
  }
  __syncthreads();

  float m = -1e30f;
  #pragma unroll
  for (int p = 0; p < 16; p++) m = fmaxf(m, lbuf[wslot][p]);
  float e[16], s = 0.f;
  #pragma unroll
  for (int p = 0; p < 16; p++) { e[p] = __expf(lbuf[wslot][p] - m); s += e[p]; }
  float inv = 1.f / s;
  if (half == 0) {
    float o = 0.f;
    #pragma unroll
    for (int p = 0; p < 16; p++) o += e[p] * vbuf[wslot][p][d];
    attn_out[(size_t)q * D_MODEL + hd] = o * inv;
  }
}

extern "C" void kernel_launch(void* const* d_in, const int* in_sizes, int n_in,
                              void* d_out, int out_size, void* d_ws, size_t ws_size,
                              hipStream_t stream) {
  const float* query = (const float*)d_in[0];
  const float* rp    = (const float*)d_in[1];
  const float* inp   = (const float*)d_in[2];
  const float* W_q   = (const float*)d_in[5];
  const float* b_q   = (const float*)d_in[6];
  const float* W_k   = (const float*)d_in[7];
  const float* b_k   = (const float*)d_in[8];
  const float* W_v   = (const float*)d_in[9];
  const float* b_v   = (const float*)d_in[10];
  const float* W_o   = (const float*)d_in[11];
  const float* b_o   = (const float*)d_in[12];
  const float* W_off = (const float*)d_in[13];
  const float* b_off = (const float*)d_in[14];
  float* out = (float*)d_out;

  const size_t nelem = (size_t)LEN_IN * D_MODEL;  // 4,264,960
  float* qp   = (float*)d_ws;
  float* offs = qp + nelem;
  float* attn = offs + nelem;
  unsigned* kvp = (unsigned*)(attn + nelem);
  unsigned short* Btk  = (unsigned short*)(kvp + nelem);
  unsigned short* Btv  = Btk + 256 * 256;
  unsigned short* Btoh = Btv + 256 * 256;
  unsigned short* Btol = Btoh + 256 * 256;

  dim3 blk(256);
  dim3 ggrid((LEN_IN + 63) / 64, D_MODEL / 64);  // (261, 4)

  prep_B<<<48, blk, 0, stream>>>(W_k, W_v, W_o, Btk, Btv, Btoh, Btol);
  gemm_f32<<<ggrid, blk, 0, stream>>>(query, W_q, b_q, qp, LEN_IN, D_MODEL, D_MODEL);
  gemm_kv_mfma<<<ggrid, blk, 0, stream>>>(inp, Btk, Btv, b_k, b_v, kvp, LEN_IN);
  gemm_f32<<<ggrid, blk, 0, stream>>>(qp, W_off, b_off, offs, LEN_IN, D_MODEL, D_MODEL);

  int n_waves = LEN_IN * N_HEADS;  // 133280
  sample_attn<<<n_waves / 4, blk, 0, stream>>>(qp, offs, rp, kvp, attn);

  gemm_o_mfma<<<ggrid, blk, 0, stream>>>(attn, Btoh, Btol, b_o, out, LEN_IN);
}

// Round 5
// 160.026 us; speedup vs baseline: 2.6147x; 2.0639x over previous
//
#include <hip/hip_runtime.h>
#include <hip/hip_bf16.h>
#include <math.h>

#define LEN_IN   16660
#define D_MODEL  256
#define N_HEADS  8
#define HEAD_DIM 32
#define N_LEVELS 4
#define N_POINTS 4

typedef __attribute__((ext_vector_type(8))) short short8v;
typedef __attribute__((ext_vector_type(4))) float f32x4;

__device__ __forceinline__ unsigned short f2bf(float f) {
  unsigned u = __float_as_uint(f);
  unsigned r = (u + 0x7fffu + ((u >> 16) & 1u)) >> 16;
  return (unsigned short)r;
}
__device__ __forceinline__ float bf2f(unsigned short h) {
  return __uint_as_float(((unsigned)h) << 16);
}

// ---------------------------------------------------------------------------
// Prep: transpose + bf16-cast 5 weight matrices. Bt[n][k] = W[k][n].
// W_q, W_off, W_o get hi+lo (residual) pairs for split-precision MFMA.
// ---------------------------------------------------------------------------
__global__ __launch_bounds__(256) void prep_B(
    const float* __restrict__ Wk, const float* __restrict__ Wv,
    const float* __restrict__ Wq, const float* __restrict__ Woff,
    const float* __restrict__ Wo,
    unsigned short* __restrict__ Btk, unsigned short* __restrict__ Btv,
    unsigned short* __restrict__ Btqh, unsigned short* __restrict__ Btql,
    unsigned short* __restrict__ Btoffh, unsigned short* __restrict__ Btoffl,
    unsigned short* __restrict__ Btoh, unsigned short* __restrict__ Btol) {
  __shared__ float tile[64][65];
  int b = blockIdx.x;
  int mat = b >> 4, t = b & 15;
  int ti = t >> 2, tj = t & 3;  // ti: k-tile, tj: n-tile
  const float* W = (mat == 0) ? Wk : (mat == 1) ? Wv : (mat == 2) ? Wq
                 : (mat == 3) ? Woff : Wo;
  int tid = threadIdx.x;
  #pragma unroll
  for (int i = 0; i < 16; i++) {
    int idx = tid + i * 256;
    int kr = idx >> 6, nc = idx & 63;
    tile[kr][nc] = W[(size_t)(ti * 64 + kr) * 256 + tj * 64 + nc];
  }
  __syncthreads();
  #pragma unroll
  for (int i = 0; i < 16; i++) {
    int idx = tid + i * 256;
    int nr = idx >> 6, kc = idx & 63;
    float v = tile[kc][nr];
    unsigned short h = f2bf(v);
    size_t o = (size_t)(tj * 64 + nr) * 256 + ti * 64 + kc;
    if (mat == 0) Btk[o] = h;
    else if (mat == 1) Btv[o] = h;
    else {
      unsigned short* Bh = (mat == 2) ? Btqh : (mat == 3) ? Btoffh : Btoh;
      unsigned short* Bl = (mat == 2) ? Btql : (mat == 3) ? Btoffl : Btol;
      Bh[o] = h;
      Bl[o] = f2bf(v - bf2f(h));
    }
  }
}

// ---------------------------------------------------------------------------
// hi/lo-split bf16 MFMA GEMM (~f32 accuracy): C = A @ Bt^T + bias, f32 out.
// A f32 (M,256) split on the fly; Bt prepped hi/lo (256,256) [n][k].
// ---------------------------------------------------------------------------
__global__ __launch_bounds__(256) void gemm_hl_mfma(
    const float* __restrict__ A,
    const unsigned short* __restrict__ Bth,
    const unsigned short* __restrict__ Btl,
    const float* __restrict__ bias, float* __restrict__ C, int M) {
  const int P = 40;
  __shared__ short Ah[64 * P], Al[64 * P], Bh[64 * P], Bl[64 * P];
  int tid = threadIdx.x;
  int m0 = blockIdx.x * 64, n0 = blockIdx.y * 64;
  int w = tid >> 6, l = tid & 63;
  int r = l & 15, g = l >> 4;
  int mi = (w >> 1) * 32, ni = (w & 1) * 32;
  int sm = tid >> 2, sp = tid & 3;

  f32x4 acc[2][2];
  #pragma unroll
  for (int a = 0; a < 2; a++)
    #pragma unroll
    for (int b = 0; b < 2; b++) acc[a][b] = (f32x4){0.f, 0.f, 0.f, 0.f};

  for (int k0 = 0; k0 < 256; k0 += 32) {
    int gm = m0 + sm;
    float f[8];
    if (gm < M) {
      const float* src = A + (size_t)gm * 256 + k0 + sp * 8;
      float4 u0 = *(const float4*)src;
      float4 u1 = *(const float4*)(src + 4);
      f[0] = u0.x; f[1] = u0.y; f[2] = u0.z; f[3] = u0.w;
      f[4] = u1.x; f[5] = u1.y; f[6] = u1.z; f[7] = u1.w;
    } else {
      #pragma unroll
      for (int j = 0; j < 8; j++) f[j] = 0.f;
    }
    short8v hv, lv;
    #pragma unroll
    for (int j = 0; j < 8; j++) {
      unsigned short h = f2bf(f[j]);
      hv[j] = (short)h;
      lv[j] = (short)f2bf(f[j] - bf2f(h));
    }
    *(short8v*)&Ah[sm * P + sp * 8] = hv;
    *(short8v*)&Al[sm * P + sp * 8] = lv;
    *(short8v*)&Bh[sm * P + sp * 8] =
        *(const short8v*)&Bth[(size_t)(n0 + sm) * 256 + k0 + sp * 8];
    *(short8v*)&Bl[sm * P + sp * 8] =
        *(const short8v*)&Btl[(size_t)(n0 + sm) * 256 + k0 + sp * 8];
    __syncthreads();

    short8v ah[2], al[2], bh[2], bl[2];
    #pragma unroll
    for (int a = 0; a < 2; a++) {
      ah[a] = *(short8v*)&Ah[(mi + a * 16 + r) * P + g * 8];
      al[a] = *(short8v*)&Al[(mi + a * 16 + r) * P + g * 8];
    }
    #pragma unroll
    for (int b = 0; b < 2; b++) {
      bh[b] = *(short8v*)&Bh[(ni + b * 16 + r) * P + g * 8];
      bl[b] = *(short8v*)&Bl[(ni + b * 16 + r) * P + g * 8];
    }
    #pragma unroll
    for (int a = 0; a < 2; a++)
      #pragma unroll
      for (int b = 0; b < 2; b++) {
        acc[a][b] = __builtin_amdgcn_mfma_f32_16x16x32_bf16(ah[a], bh[b], acc[a][b], 0, 0, 0);
        acc[a][b] = __builtin_amdgcn_mfma_f32_16x16x32_bf16(al[a], bh[b], acc[a][b], 0, 0, 0);
        acc[a][b] = __builtin_amdgcn_mfma_f32_16x16x32_bf16(ah[a], bl[b], acc[a][b], 0, 0, 0);
      }
    __syncthreads();
  }

  #pragma unroll
  for (int a = 0; a < 2; a++)
    #pragma unroll
    for (int b = 0; b < 2; b++) {
      int col = n0 + ni + b * 16 + r;
      float bc = bias[col];
      #pragma unroll
      for (int i = 0; i < 4; i++) {
        int row = m0 + mi + a * 16 + g * 4 + i;
        if (row < M) C[(size_t)row * 256 + col] = acc[a][b][i] + bc;
      }
    }
}

// ---------------------------------------------------------------------------
// Fused K+V projection, bf16 MFMA, hi/lo on A; packed bf16 {k|v<<16} out.
// ---------------------------------------------------------------------------
__global__ __launch_bounds__(256) void gemm_kv_mfma(
    const float* __restrict__ A,
    const unsigned short* __restrict__ Btk,
    const unsigned short* __restrict__ Btv,
    const float* __restrict__ bk, const float* __restrict__ bv,
    unsigned* __restrict__ kvout, int M) {
  const int P = 40;
  __shared__ short Ah[64 * P], Al[64 * P], Bk[64 * P], Bv[64 * P];
  int tid = threadIdx.x;
  int m0 = blockIdx.x * 64, n0 = blockIdx.y * 64;
  int w = tid >> 6, l = tid & 63;
  int r = l & 15, g = l >> 4;
  int mi = (w >> 1) * 32, ni = (w & 1) * 32;
  int sm = tid >> 2, sp = tid & 3;

  f32x4 acck[2][2], accv[2][2];
  #pragma unroll
  for (int a = 0; a < 2; a++)
    #pragma unroll
    for (int b = 0; b < 2; b++) {
      acck[a][b] = (f32x4){0.f, 0.f, 0.f, 0.f};
      accv[a][b] = (f32x4){0.f, 0.f, 0.f, 0.f};
    }

  for (int k0 = 0; k0 < 256; k0 += 32) {
    int gm = m0 + sm;
    float f[8];
    if (gm < M) {
      const float* src = A + (size_t)gm * 256 + k0 + sp * 8;
      float4 u0 = *(const float4*)src;
      float4 u1 = *(const float4*)(src + 4);
      f[0] = u0.x; f[1] = u0.y; f[2] = u0.z; f[3] = u0.w;
      f[4] = u1.x; f[5] = u1.y; f[6] = u1.z; f[7] = u1.w;
    } else {
      #pragma unroll
      for (int j = 0; j < 8; j++) f[j] = 0.f;
    }
    short8v hv, lv;
    #pragma unroll
    for (int j = 0; j < 8; j++) {
      unsigned short h = f2bf(f[j]);
      hv[j] = (short)h;
      lv[j] = (short)f2bf(f[j] - bf2f(h));
    }
    *(short8v*)&Ah[sm * P + sp * 8] = hv;
    *(short8v*)&Al[sm * P + sp * 8] = lv;
    *(short8v*)&Bk[sm * P + sp * 8] =
        *(const short8v*)&Btk[(size_t)(n0 + sm) * 256 + k0 + sp * 8];
    *(short8v*)&Bv[sm * P + sp * 8] =
        *(const short8v*)&Btv[(size_t)(n0 + sm) * 256 + k0 + sp * 8];
    __syncthreads();

    short8v ah[2], al[2], fbk[2], fbv[2];
    #pragma unroll
    for (int a = 0; a < 2; a++) {
      ah[a] = *(short8v*)&Ah[(mi + a * 16 + r) * P + g * 8];
      al[a] = *(short8v*)&Al[(mi + a * 16 + r) * P + g * 8];
    }
    #pragma unroll
    for (int b = 0; b < 2; b++) {
      fbk[b] = *(short8v*)&Bk[(ni + b * 16 + r) * P + g * 8];
      fbv[b] = *(short8v*)&Bv[(ni + b * 16 + r) * P + g * 8];
    }
    #pragma unroll
    for (int a = 0; a < 2; a++)
      #pragma unroll
      for (int b = 0; b < 2; b++) {
        acck[a][b] = __builtin_amdgcn_mfma_f32_16x16x32_bf16(ah[a], fbk[b], acck[a][b], 0, 0, 0);
        acck[a][b] = __builtin_amdgcn_mfma_f32_16x16x32_bf16(al[a], fbk[b], acck[a][b], 0, 0, 0);
        accv[a][b] = __builtin_amdgcn_mfma_f32_16x16x32_bf16(ah[a], fbv[b], accv[a][b], 0, 0, 0);
        accv[a][b] = __builtin_amdgcn_mfma_f32_16x16x32_bf16(al[a], fbv[b], accv[a][b], 0, 0, 0);
      }
    __syncthreads();
  }

  #pragma unroll
  for (int a = 0; a < 2; a++)
    #pragma unroll
    for (int b = 0; b < 2; b++) {
      int col = n0 + ni + b * 16 + r;
      float bkc = bk[col], bvc = bv[col];
      #pragma unroll
      for (int i = 0; i < 4; i++) {
        int row = m0 + mi + a * 16 + g * 4 + i;
        if (row < M) {
          unsigned pk = f2bf(acck[a][b][i] + bkc);
          unsigned pv = f2bf(accv[a][b][i] + bvc);
          kvout[(size_t)row * 256 + col] = pk | (pv << 16);
        }
      }
    }
}

// ---------------------------------------------------------------------------
// Sampling + attention v2: one wave per (query, head).
// Lane = (point lane>>3, channel chunk (lane&7)*4). 2 iterations x 8 points.
// Each tap: one dwordx4 load of 4 packed {k,v} channels. Address/weight math
// redundancy is 8x (was 32x); dot reduce is 3 shfl (was 5x8).
// ---------------------------------------------------------------------------
__global__ __launch_bounds__(256) void sample_attn(
    const float* __restrict__ qp,
    const float* __restrict__ offs,
    const float* __restrict__ rp,
    const unsigned* __restrict__ kv,
    float* __restrict__ attn_out) {
  __shared__ float lbuf[4][16];
  __shared__ float ebuf[4][16];
  __shared__ float vbuf[4][16][32];

  int tid = threadIdx.x;
  int wslot = tid >> 6;
  int lane = tid & 63;
  int wid = blockIdx.x * 4 + wslot;
  int q = wid >> 3;
  int h = wid & 7;

  int pt8 = lane >> 3;       // point within iteration (0..7)
  int c4 = (lane & 7) * 4;   // channel chunk base (0,4,..,28)
  int l5 = lane & 31;

  float offv = offs[(size_t)q * D_MODEL + h * 32 + l5];
  float rpv = (l5 < 8) ? rp[(size_t)q * 8 + l5] : 0.f;
  const float SCALE = 0.17677669529663687f;  // 1/sqrt(32)
  float4 q4 = *(const float4*)(qp + (size_t)q * D_MODEL + h * 32 + c4);
  q4.x *= SCALE; q4.y *= SCALE; q4.z *= SCALE; q4.w *= SCALE;
  int hoff = h * 32 + c4;

  #pragma unroll
  for (int it = 0; it < 2; it++) {
    int pt = it * 8 + pt8;
    int l = pt >> 2, pp = pt & 3;
    int W = 112 >> l;  // H == W for all levels
    int start = (int)((50176u - (50176u >> (2 * l))) / 3u);  // 0,12544,15680,16464

    float off_x = __shfl(offv, l * 8 + pp * 2 + 0, 64);
    float off_y = __shfl(offv, l * 8 + pp * 2 + 1, 64);
    float rp_x = __shfl(rpv, l * 2 + 0, 64);
    float rp_y = __shfl(rpv, l * 2 + 1, 64);

    // x = loc_x*W - 0.5 with loc_x = rp_x + off_x/W  ->  rp_x*W + off_x - 0.5
    float x = rp_x * (float)W + off_x - 0.5f;
    float y = rp_y * (float)W + off_y - 0.5f;
    float x0f = floorf(x), y0f = floorf(y);
    float lx = x - x0f, ly = y - y0f;
    int x0 = (int)x0f, y0 = (int)y0f;
    float wx0 = 1.f - lx, wy0 = 1.f - ly;
    float tw0 = wy0 * wx0, tw1 = wy0 * lx, tw2 = ly * wx0, tw3 = ly * lx;

    f32x4 kacc = {0.f, 0.f, 0.f, 0.f}, vacc = {0.f, 0.f, 0.f, 0.f};
    #pragma unroll
    for (int tap = 0; tap < 4; tap++) {
      int yy = y0 + (tap >> 1), xx = x0 + (tap & 1);
      bool valid = ((unsigned)xx < (unsigned)W) & ((unsigned)yy < (unsigned)W);
      float wgt = tap == 0 ? tw0 : tap == 1 ? tw1 : tap == 2 ? tw2 : tw3;
      wgt = valid ? wgt : 0.f;
      int pix = valid ? (start + yy * W + xx) : start;
      uint4 wv = *(const uint4*)(kv + (size_t)pix * D_MODEL + hoff);
      kacc[0] += wgt * __uint_as_float(wv.x << 16);
      kacc[1] += wgt * __uint_as_float(wv.y << 16);
      kacc[2] += wgt * __uint_as_float(wv.z << 16);
      kacc[3] += wgt * __uint_as_float(wv.w << 16);
      vacc[0] += wgt * __uint_as_float(wv.x & 0xffff0000u);
      vacc[1] += wgt * __uint_as_float(wv.y & 0xffff0000u);
      vacc[2] += wgt * __uint_as_float(wv.z & 0xffff0000u);
      vacc[3] += wgt * __uint_as_float(wv.w & 0xffff0000u);
    }

    float dot = q4.x * kacc[0] + q4.y * kacc[1] + q4.z * kacc[2] + q4.w * kacc[3];
    dot += __shfl_xor(dot, 1, 64);
    dot += __shfl_xor(dot, 2, 64);
    dot += __shfl_xor(dot, 4, 64);
    if ((lane & 7) == 0) lbuf[wslot][pt] = dot;
    *(f32x4*)&vbuf[wslot][pt][c4] = vacc;
  }
  __syncthreads();

  // softmax over 16 points: redundant across 16-lane groups, 1 exp per lane
  float lg = lbuf[wslot][lane & 15];
  float m = lg;
  m = fmaxf(m, __shfl_xor(m, 1, 64));
  m = fmaxf(m, __shfl_xor(m, 2, 64));
  m = fmaxf(m, __shfl_xor(m, 4, 64));
  m = fmaxf(m, __shfl_xor(m, 8, 64));
  float e = __expf(lg - m);
  float s = e;
  s += __shfl_xor(s, 1, 64);
  s += __shfl_xor(s, 2, 64);
  s += __shfl_xor(s, 4, 64);
  s += __shfl_xor(s, 8, 64);
  if (lane < 16) ebuf[wslot][lane] = e;
  float inv = 1.f / s;
  __syncthreads();

  if (lane < 32) {
    float o = 0.f;
    #pragma unroll
    for (int p = 0; p < 16; p++) o += ebuf[wslot][p] * vbuf[wslot][p][lane];
    attn_out[(size_t)q * D_MODEL + h * 32 + lane] = o * inv;
  }
}

extern "C" void kernel_launch(void* const* d_in, const int* in_sizes, int n_in,
                              void* d_out, int out_size, void* d_ws, size_t ws_size,
                              hipStream_t stream) {
  const float* query = (const float*)d_in[0];
  const float* rp    = (const float*)d_in[1];
  const float* inp   = (const float*)d_in[2];
  const float* W_q   = (const float*)d_in[5];
  const float* b_q   = (const float*)d_in[6];
  const float* W_k   = (const float*)d_in[7];
  const float* b_k   = (const float*)d_in[8];
  const float* W_v   = (const float*)d_in[9];
  const float* b_v   = (const float*)d_in[10];
  const float* W_o   = (const float*)d_in[11];
  const float* b_o   = (const float*)d_in[12];
  const float* W_off = (const float*)d_in[13];
  const float* b_off = (const float*)d_in[14];
  float* out = (float*)d_out;

  const size_t nelem = (size_t)LEN_IN * D_MODEL;  // 4,264,960
  float* qp   = (float*)d_ws;
  float* offs = qp + nelem;
  float* attn = offs + nelem;
  unsigned* kvp = (unsigned*)(attn + nelem);
  unsigned short* Btk    = (unsigned short*)(kvp + nelem);
  unsigned short* Btv    = Btk + 256 * 256;
  unsigned short* Btqh   = Btv + 256 * 256;
  unsigned short* Btql   = Btqh + 256 * 256;
  unsigned short* Btoffh = Btql + 256 * 256;
  unsigned short* Btoffl = Btoffh + 256 * 256;
  unsigned short* Btoh   = Btoffl + 256 * 256;
  unsigned short* Btol   = Btoh + 256 * 256;

  dim3 blk(256);
  dim3 ggrid((LEN_IN + 63) / 64, D_MODEL / 64);  // (261, 4)

  prep_B<<<80, blk, 0, stream>>>(W_k, W_v, W_q, W_off, W_o,
                                 Btk, Btv, Btqh, Btql, Btoffh, Btoffl, Btoh, Btol);
  gemm_hl_mfma<<<ggrid, blk, 0, stream>>>(query, Btqh, Btql, b_q, qp, LEN_IN);
  gemm_kv_mfma<<<ggrid, blk, 0, stream>>>(inp, Btk, Btv, b_k, b_v, kvp, LEN_IN);
  gemm_hl_mfma<<<ggrid, blk, 0, stream>>>(qp, Btoffh, Btoffl, b_off, offs, LEN_IN);

  int n_blocks = LEN_IN * N_HEADS / 4;  // 33320
  sample_attn<<<n_blocks, blk, 0, stream>>>(qp, offs, rp, kvp, attn);

  gemm_hl_mfma<<<ggrid, blk, 0, stream>>>(attn, Btoh, Btol, b_o, out, LEN_IN);
}